// Round 1
// baseline (11.037 us; speedup 1.0000x reference)
//
#include <hip/hip_runtime.h>

// Reference analysis: reference(F_T, F_I, p0) computes a homography inverse,
// grid_sample, and gradients — but `del`s the gradients and returns `p`,
// which is bound to `p0` and never reassigned. The entire body is dead code.
// Output = p0 verbatim: (B=16, 8) float32 -> 128 elements.
//
// Input order (setup_inputs dict): d_in[0]=F_T (16*1*1024*1024 f32),
// d_in[1]=F_I (same), d_in[2]=p0 (128 f32). d_out: 128 f32.

__global__ void copy_p0_kernel(const float* __restrict__ p0,
                               float* __restrict__ out, int n) {
    int i = blockIdx.x * blockDim.x + threadIdx.x;
    if (i < n) out[i] = p0[i];
}

extern "C" void kernel_launch(void* const* d_in, const int* in_sizes, int n_in,
                              void* d_out, int out_size, void* d_ws, size_t ws_size,
                              hipStream_t stream) {
    const float* p0 = (const float*)d_in[2];
    float* out = (float*)d_out;
    const int n = out_size;  // 128
    copy_p0_kernel<<<dim3((n + 127) / 128), dim3(128), 0, stream>>>(p0, out, n);
}